// Round 1
// baseline (163.189 us; speedup 1.0000x reference)
//
#include <hip/hip_runtime.h>

// Fused 34->128->128->1 MLP with embedding lerp-gather, bf16 MFMA.
// Wave layout: block=256 thr=4 waves; wave (mh,nh) computes points
// [mh*32, mh*32+32) x hidden cols [nh*64, nh*64+64) per 64-point tile.
// Weights held as MFMA B-fragments in VGPRs (one-time load per block).

using bf16x8 = __attribute__((ext_vector_type(8))) short;   // 8 bf16 = 4 VGPRs
using f32x4  = __attribute__((ext_vector_type(4))) float;   // MFMA C/D

#define NPTS    1000000
#define NUMEMB  6572
#define HID     128
#define M_IT    64          // points per block-iteration
#define A0S     72          // A0 row stride in bf16 (64 + 8 pad)
#define H0S     136         // H0 row stride in bf16 (128 + 8 pad)
#define TILES   (NPTS / M_IT)   // 15625 exactly
#define NBLOCKS 512

__device__ __forceinline__ unsigned short bf16r(float f) {
    // round-to-nearest-even f32 -> bf16 (no NaN inputs in this problem)
    unsigned u = __builtin_bit_cast(unsigned, f);
    u = (u + 0x7fffu + ((u >> 16) & 1u)) >> 16;
    return (unsigned short)u;
}
__device__ __forceinline__ unsigned pk2(float a, float b) {
    return (unsigned)bf16r(a) | ((unsigned)bf16r(b) << 16);
}

__global__ __launch_bounds__(256, 2)
void mlp_fused(const float* __restrict__ x,
               const float* __restrict__ emb,
               const float* __restrict__ em_table,
               const float* __restrict__ W0, const float* __restrict__ b0,
               const float* __restrict__ W1, const float* __restrict__ b1,
               const float* __restrict__ W2, const float* __restrict__ b2,
               float* __restrict__ out)
{
    __shared__ __align__(16) unsigned short A0[M_IT * A0S];  // bf16 bits
    __shared__ __align__(16) unsigned short H0[M_IT * H0S];  // bf16 bits
    __shared__ float PART[M_IT * 2];

    const int tid  = threadIdx.x;
    const int lane = tid & 63;
    const int w    = tid >> 6;
    const int mh   = w & 1;      // point-half
    const int nh   = w >> 1;     // hidden-half
    const int q    = lane >> 4;  // quad within wave
    const int cl   = lane & 15;

    // zero A0 once (cols 34..71 stay zero forever; build overwrites 0..33)
    for (int i = tid; i < M_IT * A0S; i += 256) A0[i] = 0;

    // ---- one-time: weight B-fragments into registers ----
    // Input dim order is [em(32), x(2), pad] => W0 logical row k maps to:
    //   k<32 -> W0 row 2+k ; k==32 -> row 0 ; k==33 -> row 1 ; k>=34 -> 0
    bf16x8 w0f[2][4];
    for (int kt = 0; kt < 2; ++kt)
        for (int j = 0; j < 4; ++j) {
            const int n = (nh * 4 + j) * 16 + cl;
            bf16x8 v;
            #pragma unroll
            for (int e = 0; e < 8; ++e) {
                const int k = kt * 32 + q * 8 + e;
                float val = 0.f;
                if (k < 32)       val = W0[(2 + k) * HID + n];
                else if (k == 32) val = W0[0 * HID + n];
                else if (k == 33) val = W0[1 * HID + n];
                v[e] = (short)bf16r(val);
            }
            w0f[kt][j] = v;
        }

    bf16x8 w1f[4][4];
    for (int kt = 0; kt < 4; ++kt)
        for (int j = 0; j < 4; ++j) {
            const int n = (nh * 4 + j) * 16 + cl;
            bf16x8 v;
            #pragma unroll
            for (int e = 0; e < 8; ++e) {
                const int k = kt * 32 + q * 8 + e;
                v[e] = (short)bf16r(W1[k * HID + n]);
            }
            w1f[kt][j] = v;
        }

    float b0f[4], b1f[4], w2f[4];
    for (int j = 0; j < 4; ++j) {
        const int n = (nh * 4 + j) * 16 + cl;
        b0f[j] = b0[n];
        b1f[j] = b1[n];
        w2f[j] = W2[n];
    }
    const float bias2 = b2[0];

    __syncthreads();   // A0 zeroing visible before first build

    for (int t = blockIdx.x; t < TILES; t += gridDim.x) {
        const int base = t * M_IT;

        // ---- stage inputs into A0 (4 threads per point) ----
        {
            const int p  = tid >> 2;
            const int s  = tid & 3;
            const int gp = base + p;
            const float fe = emb[gp];
            const int e1 = (int)fe;
            int e2 = e1 + 1; if (e2 > NUMEMB - 1) e2 = NUMEMB - 1;
            const float r = fe - (float)e1;
            const float4* p1 = (const float4*)(em_table + e1 * 32 + s * 8);
            const float4* p2 = (const float4*)(em_table + e2 * 32 + s * 8);
            const float4 a0v = p1[0], a1v = p1[1];
            const float4 c0v = p2[0], c1v = p2[1];
            uint4 d;
            d.x = pk2(a0v.x + (c0v.x - a0v.x) * r, a0v.y + (c0v.y - a0v.y) * r);
            d.y = pk2(a0v.z + (c0v.z - a0v.z) * r, a0v.w + (c0v.w - a0v.w) * r);
            d.z = pk2(a1v.x + (c1v.x - a1v.x) * r, a1v.y + (c1v.y - a1v.y) * r);
            d.w = pk2(a1v.z + (c1v.z - a1v.z) * r, a1v.w + (c1v.w - a1v.w) * r);
            *(uint4*)&A0[p * A0S + s * 8] = d;
            if (s == 0) {
                const float2 xv = *(const float2*)(x + 2 * gp);
                *(unsigned*)&A0[p * A0S + 32] = pk2(xv.x, xv.y);
            }
        }
        __syncthreads();

        // ---- layer 0: [64 x 64pad] @ [64 x 128] ----
        f32x4 acc0[2][4];
        #pragma unroll
        for (int mt = 0; mt < 2; ++mt)
            #pragma unroll
            for (int j = 0; j < 4; ++j) acc0[mt][j] = (f32x4){0.f, 0.f, 0.f, 0.f};
        #pragma unroll
        for (int mt = 0; mt < 2; ++mt) {
            const int row = mh * 32 + mt * 16 + cl;
            #pragma unroll
            for (int kt = 0; kt < 2; ++kt) {
                bf16x8 a = *(const bf16x8*)&A0[row * A0S + kt * 32 + q * 8];
                #pragma unroll
                for (int j = 0; j < 4; ++j)
                    acc0[mt][j] = __builtin_amdgcn_mfma_f32_16x16x32_bf16(
                        a, w0f[kt][j], acc0[mt][j], 0, 0, 0);
            }
        }
        // epilogue: bias + clip01 + cvt bf16 -> H0 (C-layout scatter)
        #pragma unroll
        for (int mt = 0; mt < 2; ++mt)
            #pragma unroll
            for (int j = 0; j < 4; ++j) {
                const int col = (nh * 4 + j) * 16 + cl;
                #pragma unroll
                for (int r = 0; r < 4; ++r) {
                    float h = acc0[mt][j][r] + b0f[j];
                    h = fminf(fmaxf(h, 0.f), 1.f);
                    const int row = mh * 32 + mt * 16 + q * 4 + r;
                    H0[row * H0S + col] = bf16r(h);
                }
            }
        __syncthreads();

        // ---- layer 1: [64 x 128] @ [128 x 128] ----
        f32x4 acc1[2][4];
        #pragma unroll
        for (int mt = 0; mt < 2; ++mt)
            #pragma unroll
            for (int j = 0; j < 4; ++j) acc1[mt][j] = (f32x4){0.f, 0.f, 0.f, 0.f};
        #pragma unroll
        for (int mt = 0; mt < 2; ++mt) {
            const int row = mh * 32 + mt * 16 + cl;
            #pragma unroll
            for (int kt = 0; kt < 4; ++kt) {
                bf16x8 a = *(const bf16x8*)&H0[row * H0S + kt * 32 + q * 8];
                #pragma unroll
                for (int j = 0; j < 4; ++j)
                    acc1[mt][j] = __builtin_amdgcn_mfma_f32_16x16x32_bf16(
                        a, w1f[kt][j], acc1[mt][j], 0, 0, 0);
            }
        }

        // ---- layer 1 epilogue + layer 2 dot (fp32 VALU) ----
        #pragma unroll
        for (int mt = 0; mt < 2; ++mt) {
            float sr0 = 0.f, sr1 = 0.f, sr2 = 0.f, sr3 = 0.f;
            #pragma unroll
            for (int j = 0; j < 4; ++j) {
                const f32x4 v = acc1[mt][j];
                const float h0v = fminf(fmaxf(v[0] + b1f[j], 0.f), 1.f);
                const float h1v = fminf(fmaxf(v[1] + b1f[j], 0.f), 1.f);
                const float h2v = fminf(fmaxf(v[2] + b1f[j], 0.f), 1.f);
                const float h3v = fminf(fmaxf(v[3] + b1f[j], 0.f), 1.f);
                sr0 += h0v * w2f[j];
                sr1 += h1v * w2f[j];
                sr2 += h2v * w2f[j];
                sr3 += h3v * w2f[j];
            }
            // reduce over the 16 lanes sharing q (cols); stays within quad
            #pragma unroll
            for (int msk = 1; msk < 16; msk <<= 1) {
                sr0 += __shfl_xor(sr0, msk);
                sr1 += __shfl_xor(sr1, msk);
                sr2 += __shfl_xor(sr2, msk);
                sr3 += __shfl_xor(sr3, msk);
            }
            if (cl == 0) {
                const int rbase = mh * 32 + mt * 16 + q * 4;
                PART[(rbase + 0) * 2 + nh] = sr0;
                PART[(rbase + 1) * 2 + nh] = sr1;
                PART[(rbase + 2) * 2 + nh] = sr2;
                PART[(rbase + 3) * 2 + nh] = sr3;
            }
        }
        __syncthreads();

        if (tid < 64) {
            const float z = PART[tid * 2] + PART[tid * 2 + 1] + bias2;
            out[base + tid] = 1.f / (1.f + __expf(-z));
        }
        // no trailing sync needed: next phase touching PART/H0 is two
        // barriers away; A0 build writes only cols 0..33 (disjoint from reads)
    }
}

extern "C" void kernel_launch(void* const* d_in, const int* in_sizes, int n_in,
                              void* d_out, int out_size, void* d_ws, size_t ws_size,
                              hipStream_t stream) {
    const float* x   = (const float*)d_in[0];
    const float* emb = (const float*)d_in[1];
    const float* emt = (const float*)d_in[2];
    const float* W0  = (const float*)d_in[3];
    const float* b0  = (const float*)d_in[4];
    const float* W1  = (const float*)d_in[5];
    const float* b1  = (const float*)d_in[6];
    const float* W2  = (const float*)d_in[7];
    const float* b2  = (const float*)d_in[8];
    mlp_fused<<<NBLOCKS, 256, 0, stream>>>(x, emb, emt, W0, b0, W1, b1, W2, b2,
                                           (float*)d_out);
}